// Round 5
// baseline (1942.732 us; speedup 1.0000x reference)
//
#include <hip/hip_runtime.h>
#include <hip/hip_bf16.h>

#define N 4096
#define D 64
#define NH 4
#define NSTEP 4

typedef short bf16x8 __attribute__((ext_vector_type(8)));
typedef float f32x4 __attribute__((ext_vector_type(4)));
typedef __hip_bfloat16 bf16;
typedef unsigned long long u64;

// ws layout (bytes)
static const size_t OFF_MASK = 0;                              // NSTEP*N*64 u64 = 8 MB
static const size_t OFF_FEAT = (size_t)8 << 20;                // N*D f32 = 1 MB
static const size_t OFF_HNHI = (size_t)9 << 20;                // NH*N*D bf16 = 2 MB
static const size_t OFF_HNLO = (size_t)11 << 20;               // 2 MB
static const size_t OFF_HTHI = (size_t)13 << 20;               // 2 MB
static const size_t OFF_HTLO = (size_t)15 << 20;               // 2 MB
static const size_t OFF_HOUT = (size_t)17 << 20;               // NH*N*D f32 = 4 MB
static const size_t OFF_CM   = (size_t)21 << 20;               // NH*D f32

// Transposed mask pack: mt[row][ln][w] (u64), bit i = adj[row][w*1024 + i*16 + ln].
__global__ void k_packadj(const int* __restrict__ adj, u64* __restrict__ mt) {
    int row = blockIdx.x * 4 + (threadIdx.x >> 6);   // 0 .. NSTEP*N-1
    int lane = threadIdx.x & 63;
    const int* rowp = adj + (size_t)row * N;
    u64* out = mt + (size_t)row * 64;                // 16 ln x 4 w
    for (int w = 0; w < 4; ++w) {
        const int* base = rowp + w * 1024 + lane * 16;
        for (int ln = 0; ln < 16; ++ln) {
            u64 b = __ballot(base[ln] > 0);
            if (lane == 0) out[ln * 4 + w] = b;
        }
    }
}

// h = X @ W[head] in fp32; emit hi/lo bf16 splits of hn (row-normalized) and of h (transposed);
// accumulate per-head column mean of h (fp32) for the empty-keep fallback.
__global__ void k_phase0(const float* __restrict__ X, const float* __restrict__ W,
                         bf16* __restrict__ hnhi, bf16* __restrict__ hnlo,
                         bf16* __restrict__ hthi, bf16* __restrict__ htlo,
                         float* __restrict__ colmean) {
    __shared__ float Xs[64][65];
    __shared__ float Wsh[64][64];
    __shared__ float colsum[64];
    int head = blockIdx.y;
    int r0 = blockIdx.x * 64;
    int t = threadIdx.x;
    for (int i = 0; i < 16; ++i) {
        int idx = t + 256 * i;
        int r = idx >> 6, c = idx & 63;
        Xs[r][c] = X[(size_t)(r0 + r) * 64 + c];
        Wsh[r][c] = W[(size_t)head * 4096 + idx];
    }
    if (t < 64) colsum[t] = 0.f;
    __syncthreads();
    int lane = t & 63, w = t >> 6;
    int lr = w * 16 + (lane >> 2);
    int e0 = (lane & 3) * 16;
    float acc[16];
#pragma unroll
    for (int j = 0; j < 16; ++j) acc[j] = 0.f;
    for (int d = 0; d < 64; ++d) {
        float xv = Xs[lr][d];
#pragma unroll
        for (int j = 0; j < 16; ++j) acc[j] = fmaf(xv, Wsh[d][e0 + j], acc[j]);
    }
    float ss = 0.f;
#pragma unroll
    for (int j = 0; j < 16; ++j) ss = fmaf(acc[j], acc[j], ss);
    ss += __shfl_xor(ss, 1, 64);
    ss += __shfl_xor(ss, 2, 64);
    float rn = 1.0f / (sqrtf(ss) + 1e-12f);
    int row = r0 + lr;
#pragma unroll
    for (int j = 0; j < 16; ++j) {
        float hv = acc[j];
        bf16 hhi = __float2bfloat16(hv);
        bf16 hlo = __float2bfloat16(hv - __bfloat162float(hhi));
        size_t tidx = (size_t)head * N * 64 + (size_t)(e0 + j) * N + row;
        hthi[tidx] = hhi;
        htlo[tidx] = hlo;
        float hnv = hv * rn;
        bf16 nhi = __float2bfloat16(hnv);
        bf16 nlo = __float2bfloat16(hnv - __bfloat162float(nhi));
        size_t nidx = ((size_t)head * N + row) * 64 + e0 + j;
        hnhi[nidx] = nhi;
        hnlo[nidx] = nlo;
    }
#pragma unroll
    for (int j = 0; j < 16; ++j) {
        float v = acc[j];
        v += __shfl_xor(v, 4, 64);
        v += __shfl_xor(v, 8, 64);
        v += __shfl_xor(v, 16, 64);
        v += __shfl_xor(v, 32, 64);
        if ((lane >> 2) == 0) atomicAdd(&colsum[e0 + j], v);
    }
    __syncthreads();
    if (t < 64) atomicAdd(&colmean[head * 64 + t], colsum[t] * (1.0f / N));
}

struct BFrag { bf16x8 h0, h1, l0, l1; };

__device__ __forceinline__ BFrag load_bfrag(const bf16* __restrict__ hih,
                                            const bf16* __restrict__ loh,
                                            int ct, int ln, int quad) {
    BFrag f;
    const bf16* ph = hih + (size_t)((ct << 4) + ln) * 64 + quad * 8;
    const bf16* pl = loh + (size_t)((ct << 4) + ln) * 64 + quad * 8;
    f.h0 = *(const bf16x8*)(ph);
    f.h1 = *(const bf16x8*)(ph + 32);
    f.l0 = *(const bf16x8*)(pl);
    f.l1 = *(const bf16x8*)(pl + 32);
    return f;
}

// split-bf16 sim: s = hi*hi + lo*hi + hi*lo (fp32 accumulate); identical sequence in
// both passes so the keep rule compares bit-identical values.
__device__ __forceinline__ f32x4 sim_mfma(const BFrag& b,
                                          bf16x8 a0h, bf16x8 a1h, bf16x8 a0l, bf16x8 a1l) {
    f32x4 s = {0.f, 0.f, 0.f, 0.f};
    s = __builtin_amdgcn_mfma_f32_16x16x32_bf16(a0h, b.h0, s, 0, 0, 0);
    s = __builtin_amdgcn_mfma_f32_16x16x32_bf16(a1h, b.h1, s, 0, 0, 0);
    s = __builtin_amdgcn_mfma_f32_16x16x32_bf16(a0l, b.h0, s, 0, 0, 0);
    s = __builtin_amdgcn_mfma_f32_16x16x32_bf16(a1l, b.h1, s, 0, 0, 0);
    s = __builtin_amdgcn_mfma_f32_16x16x32_bf16(a0h, b.l0, s, 0, 0, 0);
    s = __builtin_amdgcn_mfma_f32_16x16x32_bf16(a1h, b.l1, s, 0, 0, 0);
    return s;
}

// fused two-pass masked attention. Block = 16 rows of one head; 4 waves split the
// 4096 columns (1024 each). Fat iterations: 4 column-tiles (64 cols) per loop body,
// 4 independent MFMA chains, batched loads, register-resident masks, no copy-prefetch.
__launch_bounds__(256, 4)
__global__ void k_attn(const bf16* __restrict__ hnhi, const bf16* __restrict__ hnlo,
                       const bf16* __restrict__ hthi, const bf16* __restrict__ htlo,
                       const u64* __restrict__ mt,
                       const float* __restrict__ colmean,
                       float* __restrict__ hout) {
    __shared__ bf16 Plds[4][16 * 68];      // per-wave P tile (16 rows x 64 cols, stride 68)
    __shared__ float maxb[4][16];
    __shared__ float lbuf[4][16];
    __shared__ float pvbuf[4][16][66];     // per-wave PV partials, padded stride
    int bid = blockIdx.x;
    int head = (bid & 7) >> 1;
    int rw = (((bid >> 3) << 1) | (bid & 1)) * 16;
    int t = threadIdx.x;
    int w = t >> 6, lane = t & 63;
    int ln = lane & 15, quad = lane >> 4;
    const bf16* hih = hnhi + (size_t)head * N * 64;
    const bf16* loh = hnlo + (size_t)head * N * 64;
    // A fragments (hi and lo) for the block's 16 rows, k=0..31 and 32..63
    bf16x8 a0h = *(const bf16x8*)(hih + (size_t)(rw + ln) * 64 + quad * 8);
    bf16x8 a1h = *(const bf16x8*)(hih + (size_t)(rw + ln) * 64 + 32 + quad * 8);
    bf16x8 a0l = *(const bf16x8*)(loh + (size_t)(rw + ln) * 64 + quad * 8);
    bf16x8 a1l = *(const bf16x8*)(loh + (size_t)(rw + ln) * 64 + 32 + quad * 8);
    // register-resident masks: 4 u64 per lane
    u64 mreg[4];
#pragma unroll
    for (int r = 0; r < 4; ++r)
        mreg[r] = mt[((size_t)(rw + quad * 4 + r) * 16 + ln) * 4 + w];

    const float NEGINF = -__builtin_inff();
    float m4[4] = {NEGINF, NEGINF, NEGINF, NEGINF};
    int ct0 = w * 64;   // this wave's 64 column tiles (1024 columns)

    // PASS A: masked row-max. 16 fat iterations x 4 column-tiles.
    for (int fi = 0; fi < 16; ++fi) {
        int ct = ct0 + fi * 4;
        BFrag bt[4];
#pragma unroll
        for (int tt = 0; tt < 4; ++tt) bt[tt] = load_bfrag(hih, loh, ct + tt, ln, quad);
        f32x4 s[4];
#pragma unroll
        for (int tt = 0; tt < 4; ++tt) s[tt] = sim_mfma(bt[tt], a0h, a1h, a0l, a1l);
#pragma unroll
        for (int tt = 0; tt < 4; ++tt) {
            int bi = fi * 4 + tt;
#pragma unroll
            for (int r = 0; r < 4; ++r) {
                unsigned int bit = (unsigned int)(mreg[r] >> bi) & 1u;
                float v = bit ? s[tt][r] : NEGINF;
                m4[r] = fmaxf(m4[r], v);
            }
        }
    }
#pragma unroll
    for (int r = 0; r < 4; ++r) {
        float v = m4[r];
        v = fmaxf(v, __shfl_xor(v, 1, 64));
        v = fmaxf(v, __shfl_xor(v, 2, 64));
        v = fmaxf(v, __shfl_xor(v, 4, 64));
        v = fmaxf(v, __shfl_xor(v, 8, 64));
        if (ln == 0) maxb[w][quad * 4 + r] = v;
    }
    __syncthreads();
#pragma unroll
    for (int r = 0; r < 4; ++r) {
        int row = quad * 4 + r;
        m4[r] = fmaxf(fmaxf(maxb[0][row], maxb[1][row]), fmaxf(maxb[2][row], maxb[3][row]));
    }

    // PASS B: recompute (bit-identical), keep rule, exp, partial l and partial PV.
    // 16 fat iterations: 64-col sim tile -> P (LDS) -> 16 PV MFMAs.
    const bf16* thih = hthi + (size_t)head * N * 64;
    const bf16* tloh = htlo + (size_t)head * N * 64;
    float l4[4] = {0.f, 0.f, 0.f, 0.f};
    f32x4 pv[4];
#pragma unroll
    for (int nt = 0; nt < 4; ++nt) pv[nt] = (f32x4){0.f, 0.f, 0.f, 0.f};
    bf16* P = &Plds[w][0];
    for (int fi = 0; fi < 16; ++fi) {
        int ct = ct0 + fi * 4;
        BFrag bt[4];
#pragma unroll
        for (int tt = 0; tt < 4; ++tt) bt[tt] = load_bfrag(hih, loh, ct + tt, ln, quad);
        f32x4 s[4];
#pragma unroll
        for (int tt = 0; tt < 4; ++tt) s[tt] = sim_mfma(bt[tt], a0h, a1h, a0l, a1l);
#pragma unroll
        for (int tt = 0; tt < 4; ++tt) {
            int bi = fi * 4 + tt;
#pragma unroll
            for (int r = 0; r < 4; ++r) {
                unsigned int bit = (unsigned int)(mreg[r] >> bi) & 1u;
                bool keep = bit && (s[tt][r] >= 0.5f * m4[r]);
                float arg = keep ? 5.0f * (s[tt][r] - m4[r]) : NEGINF;
                float p = __expf(arg);
                bf16 pb = __float2bfloat16(p);
                l4[r] += __bfloat162float(pb);   // denominator from the ROUNDED p
                P[(quad * 4 + r) * 68 + tt * 16 + ln] = pb;
            }
        }
        __builtin_amdgcn_wave_barrier();
        bf16x8 pa0 = *(const bf16x8*)(P + ln * 68 + quad * 8);
        bf16x8 pa1 = *(const bf16x8*)(P + ln * 68 + 32 + quad * 8);
        int cb = ct0 * 16 + fi * 64;
#pragma unroll
        for (int nt = 0; nt < 4; ++nt) {
            const bf16* bp = thih + (size_t)(nt * 16 + ln) * N + cb + quad * 8;
            const bf16* lp = tloh + (size_t)(nt * 16 + ln) * N + cb + quad * 8;
            bf16x8 bh0 = *(const bf16x8*)(bp);
            bf16x8 bh1 = *(const bf16x8*)(bp + 32);
            bf16x8 bl0 = *(const bf16x8*)(lp);
            bf16x8 bl1 = *(const bf16x8*)(lp + 32);
            pv[nt] = __builtin_amdgcn_mfma_f32_16x16x32_bf16(pa0, bh0, pv[nt], 0, 0, 0);
            pv[nt] = __builtin_amdgcn_mfma_f32_16x16x32_bf16(pa1, bh1, pv[nt], 0, 0, 0);
            pv[nt] = __builtin_amdgcn_mfma_f32_16x16x32_bf16(pa0, bl0, pv[nt], 0, 0, 0);
            pv[nt] = __builtin_amdgcn_mfma_f32_16x16x32_bf16(pa1, bl1, pv[nt], 0, 0, 0);
        }
        __builtin_amdgcn_wave_barrier();
    }
    // per-wave partials -> LDS
#pragma unroll
    for (int r = 0; r < 4; ++r) {
        float v = l4[r];
        v += __shfl_xor(v, 1, 64);
        v += __shfl_xor(v, 2, 64);
        v += __shfl_xor(v, 4, 64);
        v += __shfl_xor(v, 8, 64);
        if (ln == 0) lbuf[w][quad * 4 + r] = v;
    }
#pragma unroll
    for (int nt = 0; nt < 4; ++nt)
#pragma unroll
        for (int r = 0; r < 4; ++r)
            pvbuf[w][quad * 4 + r][nt * 16 + ln] = pv[nt][r];
    __syncthreads();

    // epilogue: reduce over waves, normalize, ELU, store (float4 per thread)
    int row = t >> 4;
    int c4 = (t & 15) * 4;
    float lsum = lbuf[0][row] + lbuf[1][row] + lbuf[2][row] + lbuf[3][row];
    float inv = (lsum > 0.f) ? 1.0f / lsum : 0.f;
    float4 o;
    float* op = &o.x;
#pragma unroll
    for (int i = 0; i < 4; ++i) {
        int col = c4 + i;
        float v = pvbuf[0][row][col] + pvbuf[1][row][col] + pvbuf[2][row][col] + pvbuf[3][row][col];
        v = (lsum > 0.f) ? v * inv : colmean[head * 64 + col];
        op[i] = (v > 0.f) ? v : (__expf(v) - 1.0f);
    }
    *(float4*)(hout + ((size_t)head * N + rw + row) * 64 + c4) = o;
}

__global__ void k_combine(const float* __restrict__ hout, float* __restrict__ feat,
                          float* __restrict__ outp, int last) {
    int i = blockIdx.x * 256 + threadIdx.x;
    float v = 0.25f * (hout[i] + hout[i + N * 64] + hout[i + 2 * N * 64] + hout[i + 3 * N * 64]);
    if (last) outp[i] = v;
    else feat[i] = v;
}

extern "C" void kernel_launch(void* const* d_in, const int* in_sizes, int n_in,
                              void* d_out, int out_size, void* d_ws, size_t ws_size,
                              hipStream_t stream) {
    const float* features_in = (const float*)d_in[0];
    const int* adj = (const int*)d_in[1];
    const float* Ws = (const float*)d_in[2];
    char* ws = (char*)d_ws;
    u64* mt = (u64*)(ws + OFF_MASK);
    float* feat = (float*)(ws + OFF_FEAT);
    bf16* hnhi = (bf16*)(ws + OFF_HNHI);
    bf16* hnlo = (bf16*)(ws + OFF_HNLO);
    bf16* hthi = (bf16*)(ws + OFF_HTHI);
    bf16* htlo = (bf16*)(ws + OFF_HTLO);
    float* hout = (float*)(ws + OFF_HOUT);
    float* cm = (float*)(ws + OFF_CM);

    k_packadj<<<dim3(NSTEP * N / 4), dim3(256), 0, stream>>>(adj, mt);
    for (int s = 0; s < NSTEP; ++s) {
        hipMemsetAsync(cm, 0, NH * D * sizeof(float), stream);
        const float* X = (s == 0) ? features_in : feat;
        k_phase0<<<dim3(64, NH), dim3(256), 0, stream>>>(X, Ws + (size_t)s * NH * D * D,
                                                         hnhi, hnlo, hthi, htlo, cm);
        k_attn<<<dim3(N / 16 * NH), dim3(256), 0, stream>>>(hnhi, hnlo, hthi, htlo,
                                                            mt + (size_t)s * N * 64, cm, hout);
        k_combine<<<dim3(N * D / 256), dim3(256), 0, stream>>>(hout, feat, (float*)d_out, s == NSTEP - 1);
    }
}

// Round 6
// 1022.087 us; speedup vs baseline: 1.9008x; 1.9008x over previous
//
#include <hip/hip_runtime.h>
#include <hip/hip_bf16.h>

#define N 4096
#define D 64
#define NH 4
#define NSTEP 4
#define HSTRIDE 262144   // elements per head in fragment-major arrays (4096*64)

typedef short bf16x8 __attribute__((ext_vector_type(8)));
typedef float f32x4 __attribute__((ext_vector_type(4)));
typedef __hip_bfloat16 bf16;
typedef unsigned long long u64;

// ws layout (bytes)
static const size_t OFF_MASK = 0;                              // NSTEP*N*64 u64 = 8 MB
static const size_t OFF_FEAT = (size_t)8 << 20;                // N*D f32 = 1 MB
static const size_t OFF_HNHI = (size_t)9 << 20;                // NH*HSTRIDE bf16 = 2 MB
static const size_t OFF_HNLO = (size_t)11 << 20;               // 2 MB
static const size_t OFF_HTHI = (size_t)13 << 20;               // 2 MB
static const size_t OFF_HTLO = (size_t)15 << 20;               // 2 MB
static const size_t OFF_HOUT = (size_t)17 << 20;               // NH*N*D f32 = 4 MB
static const size_t OFF_CM   = (size_t)21 << 20;               // NH*D f32

// Transposed mask pack: mt[row][ln][w] (u64), bit i = adj[row][w*1024 + i*16 + ln].
__global__ void k_packadj(const int* __restrict__ adj, u64* __restrict__ mt) {
    int row = blockIdx.x * 4 + (threadIdx.x >> 6);   // 0 .. NSTEP*N-1
    int lane = threadIdx.x & 63;
    const int* rowp = adj + (size_t)row * N;
    u64* out = mt + (size_t)row * 64;                // 16 ln x 4 w
    for (int w = 0; w < 4; ++w) {
        const int* base = rowp + w * 1024 + lane * 16;
        for (int ln = 0; ln < 16; ++ln) {
            u64 b = __ballot(base[ln] > 0);
            if (lane == 0) out[ln * 4 + w] = b;
        }
    }
}

// h = X @ W[head] in fp32. Emit FRAGMENT-MAJOR hi/lo bf16 splits:
//   hnf[(ct*2+half)*64 + q*16 + ln]*8 + j8  : sim fragment (col n = ct*16+ln, k = half*32+q*8+j8)
//   htf[(g*8 + nt*2 + half)*64 + q*16 + ln]*8 + j8 : PV fragment (k-col = g*64+half*32+q*8+j8, n-dim = nt*16+ln)
// so every k_attn hot load is base + lane*16B (contiguous 1KB per wave instruction).
__global__ void k_phase0(const float* __restrict__ X, const float* __restrict__ W,
                         bf16* __restrict__ hnf_hi, bf16* __restrict__ hnf_lo,
                         bf16* __restrict__ htf_hi, bf16* __restrict__ htf_lo,
                         float* __restrict__ colmean) {
    __shared__ float Xs[64][65];
    __shared__ float Wsh[64][64];
    __shared__ float colsum[64];
    int head = blockIdx.y;
    int r0 = blockIdx.x * 64;
    int t = threadIdx.x;
    for (int i = 0; i < 16; ++i) {
        int idx = t + 256 * i;
        int r = idx >> 6, c = idx & 63;
        Xs[r][c] = X[(size_t)(r0 + r) * 64 + c];
        Wsh[r][c] = W[(size_t)head * 4096 + idx];
    }
    if (t < 64) colsum[t] = 0.f;
    __syncthreads();
    int lane = t & 63, w = t >> 6;
    int lr = w * 16 + (lane >> 2);
    int e0 = (lane & 3) * 16;
    float acc[16];
#pragma unroll
    for (int j = 0; j < 16; ++j) acc[j] = 0.f;
    for (int d = 0; d < 64; ++d) {
        float xv = Xs[lr][d];
#pragma unroll
        for (int j = 0; j < 16; ++j) acc[j] = fmaf(xv, Wsh[d][e0 + j], acc[j]);
    }
    float ss = 0.f;
#pragma unroll
    for (int j = 0; j < 16; ++j) ss = fmaf(acc[j], acc[j], ss);
    ss += __shfl_xor(ss, 1, 64);
    ss += __shfl_xor(ss, 2, 64);
    float rn = 1.0f / (sqrtf(ss) + 1e-12f);
    int row = r0 + lr;
    size_t hb = (size_t)head * HSTRIDE;
#pragma unroll
    for (int j = 0; j < 16; ++j) {
        int d = e0 + j;
        float hv = acc[j];
        bf16 hhi = __float2bfloat16(hv);
        bf16 hlo = __float2bfloat16(hv - __bfloat162float(hhi));
        // htf: PV B-fragment position (k-col = row, n-dim = d)
        int g = row >> 6, cc = row & 63;
        size_t tidx = hb + (size_t)(((g * 8 + (d >> 4) * 2 + (cc >> 5)) * 64
                                     + ((cc >> 3) & 3) * 16 + (d & 15)) * 8 + (cc & 7));
        htf_hi[tidx] = hhi;
        htf_lo[tidx] = hlo;
        float hnv = hv * rn;
        bf16 nhi = __float2bfloat16(hnv);
        bf16 nlo = __float2bfloat16(hnv - __bfloat162float(nhi));
        // hnf: sim fragment position (col n = row, k = d)
        int ct = row >> 4;
        size_t nidx = hb + (size_t)(((ct * 2 + (d >> 5)) * 64
                                     + ((d >> 3) & 3) * 16 + (row & 15)) * 8 + (d & 7));
        hnf_hi[nidx] = nhi;
        hnf_lo[nidx] = nlo;
    }
#pragma unroll
    for (int j = 0; j < 16; ++j) {
        float v = acc[j];
        v += __shfl_xor(v, 4, 64);
        v += __shfl_xor(v, 8, 64);
        v += __shfl_xor(v, 16, 64);
        v += __shfl_xor(v, 32, 64);
        if ((lane >> 2) == 0) atomicAdd(&colsum[e0 + j], v);
    }
    __syncthreads();
    if (t < 64) atomicAdd(&colmean[head * 64 + t], colsum[t] * (1.0f / N));
}

struct BFrag { bf16x8 h0, h1, l0, l1; };

// fragment-major load: 4 contiguous 1KB wave loads per tile
__device__ __forceinline__ BFrag load_bfrag(const bf16* __restrict__ hfh,
                                            const bf16* __restrict__ hfl,
                                            int ct, int lane) {
    BFrag f;
    size_t base = (size_t)(ct * 2) * 512 + lane * 8;
    f.h0 = *(const bf16x8*)(hfh + base);
    f.h1 = *(const bf16x8*)(hfh + base + 512);
    f.l0 = *(const bf16x8*)(hfl + base);
    f.l1 = *(const bf16x8*)(hfl + base + 512);
    return f;
}

// split-bf16 sim: s = hi*hi + lo*hi + hi*lo (fp32 accumulate); identical sequence in
// both passes so the keep rule compares bit-identical values.
__device__ __forceinline__ f32x4 sim_mfma(const BFrag& b,
                                          bf16x8 a0h, bf16x8 a1h, bf16x8 a0l, bf16x8 a1l) {
    f32x4 s = {0.f, 0.f, 0.f, 0.f};
    s = __builtin_amdgcn_mfma_f32_16x16x32_bf16(a0h, b.h0, s, 0, 0, 0);
    s = __builtin_amdgcn_mfma_f32_16x16x32_bf16(a1h, b.h1, s, 0, 0, 0);
    s = __builtin_amdgcn_mfma_f32_16x16x32_bf16(a0l, b.h0, s, 0, 0, 0);
    s = __builtin_amdgcn_mfma_f32_16x16x32_bf16(a1l, b.h1, s, 0, 0, 0);
    s = __builtin_amdgcn_mfma_f32_16x16x32_bf16(a0h, b.l0, s, 0, 0, 0);
    s = __builtin_amdgcn_mfma_f32_16x16x32_bf16(a1h, b.l1, s, 0, 0, 0);
    return s;
}

// fused two-pass masked attention. Block = 16 rows of one head; 4 waves split the
// 4096 columns (1024 each). All hot loads are fragment-major (contiguous 1KB/wave).
__launch_bounds__(256, 4)
__global__ void k_attn(const bf16* __restrict__ hnf_hi, const bf16* __restrict__ hnf_lo,
                       const bf16* __restrict__ htf_hi, const bf16* __restrict__ htf_lo,
                       const u64* __restrict__ mt,
                       const float* __restrict__ colmean,
                       float* __restrict__ hout) {
    __shared__ bf16 Plds[4][16 * 68];      // per-wave P tile (16 rows x 64 cols, stride 68)
    __shared__ float maxb[4][16];
    __shared__ float lbuf[4][16];
    __shared__ float pvbuf[4][16][66];     // per-wave PV partials, padded stride
    int bid = blockIdx.x;
    int head = (bid & 7) >> 1;
    int rw = (((bid >> 3) << 1) | (bid & 1)) * 16;
    int t = threadIdx.x;
    int w = t >> 6, lane = t & 63;
    int ln = lane & 15, quad = lane >> 4;
    const bf16* hfh = hnf_hi + (size_t)head * HSTRIDE;
    const bf16* hfl = hnf_lo + (size_t)head * HSTRIDE;
    // A fragments for the block's 16 rows: identical lane layout to the B fragment
    // of column-tile rw/16 (X·X^T symmetry), so load them fragment-major too.
    bf16x8 a0h, a1h, a0l, a1l;
    {
        size_t base = (size_t)((rw >> 4) * 2) * 512 + lane * 8;
        a0h = *(const bf16x8*)(hfh + base);
        a1h = *(const bf16x8*)(hfh + base + 512);
        a0l = *(const bf16x8*)(hfl + base);
        a1l = *(const bf16x8*)(hfl + base + 512);
    }
    // register-resident masks: 4 u64 per lane
    u64 mreg[4];
#pragma unroll
    for (int r = 0; r < 4; ++r)
        mreg[r] = mt[((size_t)(rw + quad * 4 + r) * 16 + ln) * 4 + w];

    const float NEGINF = -__builtin_inff();
    float m4[4] = {NEGINF, NEGINF, NEGINF, NEGINF};
    int ct0 = w * 64;   // this wave's 64 column tiles (1024 columns)

    // PASS A: masked row-max. 16 fat iterations x 4 column-tiles.
    for (int fi = 0; fi < 16; ++fi) {
        int ct = ct0 + fi * 4;
        BFrag bt[4];
#pragma unroll
        for (int tt = 0; tt < 4; ++tt) bt[tt] = load_bfrag(hfh, hfl, ct + tt, lane);
        f32x4 s[4];
#pragma unroll
        for (int tt = 0; tt < 4; ++tt) s[tt] = sim_mfma(bt[tt], a0h, a1h, a0l, a1l);
#pragma unroll
        for (int tt = 0; tt < 4; ++tt) {
            int bi = fi * 4 + tt;
#pragma unroll
            for (int r = 0; r < 4; ++r) {
                unsigned int bit = (unsigned int)(mreg[r] >> bi) & 1u;
                float v = bit ? s[tt][r] : NEGINF;
                m4[r] = fmaxf(m4[r], v);
            }
        }
    }
#pragma unroll
    for (int r = 0; r < 4; ++r) {
        float v = m4[r];
        v = fmaxf(v, __shfl_xor(v, 1, 64));
        v = fmaxf(v, __shfl_xor(v, 2, 64));
        v = fmaxf(v, __shfl_xor(v, 4, 64));
        v = fmaxf(v, __shfl_xor(v, 8, 64));
        if (ln == 0) maxb[w][quad * 4 + r] = v;
    }
    __syncthreads();
#pragma unroll
    for (int r = 0; r < 4; ++r) {
        int row = quad * 4 + r;
        m4[r] = fmaxf(fmaxf(maxb[0][row], maxb[1][row]), fmaxf(maxb[2][row], maxb[3][row]));
    }

    // PASS B: recompute (bit-identical), keep rule, exp, partial l and partial PV.
    const bf16* tfh = htf_hi + (size_t)head * HSTRIDE;
    const bf16* tfl = htf_lo + (size_t)head * HSTRIDE;
    float l4[4] = {0.f, 0.f, 0.f, 0.f};
    f32x4 pv[4];
#pragma unroll
    for (int nt = 0; nt < 4; ++nt) pv[nt] = (f32x4){0.f, 0.f, 0.f, 0.f};
    bf16* P = &Plds[w][0];
    for (int fi = 0; fi < 16; ++fi) {
        int ct = ct0 + fi * 4;
        BFrag bt[4];
#pragma unroll
        for (int tt = 0; tt < 4; ++tt) bt[tt] = load_bfrag(hfh, hfl, ct + tt, lane);
        f32x4 s[4];
#pragma unroll
        for (int tt = 0; tt < 4; ++tt) s[tt] = sim_mfma(bt[tt], a0h, a1h, a0l, a1l);
#pragma unroll
        for (int tt = 0; tt < 4; ++tt) {
            int bi = fi * 4 + tt;
#pragma unroll
            for (int r = 0; r < 4; ++r) {
                unsigned int bit = (unsigned int)(mreg[r] >> bi) & 1u;
                bool keep = bit && (s[tt][r] >= 0.5f * m4[r]);
                float arg = keep ? 5.0f * (s[tt][r] - m4[r]) : NEGINF;
                float p = __expf(arg);
                bf16 pb = __float2bfloat16(p);
                l4[r] += __bfloat162float(pb);   // denominator from the ROUNDED p
                P[(quad * 4 + r) * 68 + tt * 16 + ln] = pb;
            }
        }
        __builtin_amdgcn_wave_barrier();
        bf16x8 pa0 = *(const bf16x8*)(P + ln * 68 + quad * 8);
        bf16x8 pa1 = *(const bf16x8*)(P + ln * 68 + 32 + quad * 8);
        int g = w * 16 + fi;    // 64-col PV tile index
#pragma unroll
        for (int nt = 0; nt < 4; ++nt) {
            size_t base = (size_t)(g * 8 + nt * 2) * 512 + lane * 8;
            bf16x8 bh0 = *(const bf16x8*)(tfh + base);
            bf16x8 bh1 = *(const bf16x8*)(tfh + base + 512);
            bf16x8 bl0 = *(const bf16x8*)(tfl + base);
            bf16x8 bl1 = *(const bf16x8*)(tfl + base + 512);
            pv[nt] = __builtin_amdgcn_mfma_f32_16x16x32_bf16(pa0, bh0, pv[nt], 0, 0, 0);
            pv[nt] = __builtin_amdgcn_mfma_f32_16x16x32_bf16(pa1, bh1, pv[nt], 0, 0, 0);
            pv[nt] = __builtin_amdgcn_mfma_f32_16x16x32_bf16(pa0, bl0, pv[nt], 0, 0, 0);
            pv[nt] = __builtin_amdgcn_mfma_f32_16x16x32_bf16(pa1, bl1, pv[nt], 0, 0, 0);
        }
        __builtin_amdgcn_wave_barrier();
    }
    // per-wave partials -> LDS
#pragma unroll
    for (int r = 0; r < 4; ++r) {
        float v = l4[r];
        v += __shfl_xor(v, 1, 64);
        v += __shfl_xor(v, 2, 64);
        v += __shfl_xor(v, 4, 64);
        v += __shfl_xor(v, 8, 64);
        if (ln == 0) lbuf[w][quad * 4 + r] = v;
    }
#pragma unroll
    for (int nt = 0; nt < 4; ++nt)
#pragma unroll
        for (int r = 0; r < 4; ++r)
            pvbuf[w][quad * 4 + r][nt * 16 + ln] = pv[nt][r];
    __syncthreads();

    // epilogue: reduce over waves, normalize, ELU, store (float4 per thread)
    int row = t >> 4;
    int c4 = (t & 15) * 4;
    float lsum = lbuf[0][row] + lbuf[1][row] + lbuf[2][row] + lbuf[3][row];
    float inv = (lsum > 0.f) ? 1.0f / lsum : 0.f;
    float4 o;
    float* op = &o.x;
#pragma unroll
    for (int i = 0; i < 4; ++i) {
        int col = c4 + i;
        float v = pvbuf[0][row][col] + pvbuf[1][row][col] + pvbuf[2][row][col] + pvbuf[3][row][col];
        v = (lsum > 0.f) ? v * inv : colmean[head * 64 + col];
        op[i] = (v > 0.f) ? v : (__expf(v) - 1.0f);
    }
    *(float4*)(hout + ((size_t)head * N + rw + row) * 64 + c4) = o;
}

__global__ void k_combine(const float* __restrict__ hout, float* __restrict__ feat,
                          float* __restrict__ outp, int last) {
    int i = blockIdx.x * 256 + threadIdx.x;
    float v = 0.25f * (hout[i] + hout[i + N * 64] + hout[i + 2 * N * 64] + hout[i + 3 * N * 64]);
    if (last) outp[i] = v;
    else feat[i] = v;
}

extern "C" void kernel_launch(void* const* d_in, const int* in_sizes, int n_in,
                              void* d_out, int out_size, void* d_ws, size_t ws_size,
                              hipStream_t stream) {
    const float* features_in = (const float*)d_in[0];
    const int* adj = (const int*)d_in[1];
    const float* Ws = (const float*)d_in[2];
    char* ws = (char*)d_ws;
    u64* mt = (u64*)(ws + OFF_MASK);
    float* feat = (float*)(ws + OFF_FEAT);
    bf16* hnf_hi = (bf16*)(ws + OFF_HNHI);
    bf16* hnf_lo = (bf16*)(ws + OFF_HNLO);
    bf16* htf_hi = (bf16*)(ws + OFF_HTHI);
    bf16* htf_lo = (bf16*)(ws + OFF_HTLO);
    float* hout = (float*)(ws + OFF_HOUT);
    float* cm = (float*)(ws + OFF_CM);

    k_packadj<<<dim3(NSTEP * N / 4), dim3(256), 0, stream>>>(adj, mt);
    for (int s = 0; s < NSTEP; ++s) {
        hipMemsetAsync(cm, 0, NH * D * sizeof(float), stream);
        const float* X = (s == 0) ? features_in : feat;
        k_phase0<<<dim3(64, NH), dim3(256), 0, stream>>>(X, Ws + (size_t)s * NH * D * D,
                                                         hnf_hi, hnf_lo, htf_hi, htf_lo, cm);
        k_attn<<<dim3(N / 16 * NH), dim3(256), 0, stream>>>(hnf_hi, hnf_lo, htf_hi, htf_lo,
                                                            mt + (size_t)s * N * 64, cm, hout);
        k_combine<<<dim3(N * D / 256), dim3(256), 0, stream>>>(hout, feat, (float*)d_out, s == NSTEP - 1);
    }
}